// Round 15
// baseline (372.849 us; speedup 1.0000x reference)
//
#include <hip/hip_runtime.h>
#include <hip/hip_bf16.h>

#define BDIM 1024
#define NH 16
#define HD 64
#define BB 4
#define SS 2048
#define MTOT (BB*SS)   // 8192
#define NT (SS/64)     // 32 key tiles

typedef __bf16 bf16x8 __attribute__((ext_vector_type(8)));
typedef float f32x4 __attribute__((ext_vector_type(4)));

// native HW bf16 convert (v_cvt_pk_bf16_f32; compiler packs pairs) — RNE.
__device__ __forceinline__ unsigned short f2b(float f){
    __bf16 h = (__bf16)f;
    return __builtin_bit_cast(unsigned short, h);
}

// v_cvt_pk_bf16_f32: lo -> bits[15:0], hi -> bits[31:16], RNE (same as f2b).
__device__ __forceinline__ unsigned cvtpk(float lo, float hi){
    unsigned u;
    asm("v_cvt_pk_bf16_f32 %0, %1, %2" : "=v"(u) : "v"(lo), "v"(hi));
    return u;
}

// async global->LDS, 16B per lane. LDS dest is wave-uniform base + lane*16.
__device__ __forceinline__ void ld16(const unsigned short* g, unsigned short* l){
    __builtin_amdgcn_global_load_lds(
        (const __attribute__((address_space(1))) unsigned int*)(const void*)g,
        (__attribute__((address_space(3))) unsigned int*)(void*)l, 16, 0, 0);
}

// ---------------- merged setup: x->bf16, weights->bf16, rope table ----------------
// grid 12544 x 256: [0,8192) x-convert, [8192,12288) weights, [12288,12544) rope.
__global__ void setup_all(const float* __restrict__ x,
                          const float* __restrict__ Wq, const float* __restrict__ Wk,
                          const float* __restrict__ Wv, const float* __restrict__ Wo,
                          unsigned short* __restrict__ xb,
                          unsigned short* __restrict__ oq, unsigned short* __restrict__ ok,
                          unsigned short* __restrict__ ov, unsigned short* __restrict__ oo,
                          float2* __restrict__ rt){
    const int bid = blockIdx.x;
    const int tid = threadIdx.x;
    if (bid < 8192){
        int i = bid * 256 + tid;                       // 2,097,152 float4 chunks
        float4 v = ((const float4*)x)[i];
        ushort4 o;
        o.x = f2b(v.x); o.y = f2b(v.y); o.z = f2b(v.z); o.w = f2b(v.w);
        ((ushort4*)xb)[i] = o;
    } else if (bid < 12288){
        int idx = bid - 8192;
        int which = idx >> 10;                          // 1024 blocks per weight
        const float* in = (which == 0) ? Wq : (which == 1) ? Wk : (which == 2) ? Wv : Wo;
        unsigned short* out = (which == 0) ? oq : (which == 1) ? ok : (which == 2) ? ov : oo;
        int i = (idx & 1023) * 256 + tid;               // 262,144 float4 chunks
        float4 v = ((const float4*)in)[i];
        ushort4 o;
        o.x = f2b(v.x); o.y = f2b(v.y); o.z = f2b(v.z); o.w = f2b(v.w);
        ((ushort4*)out)[i] = o;
    } else {
        int i = (bid - 12288) * 256 + tid;              // 65,536 rope entries
        int s = i >> 5, d = i & 31;
        float theta = (float)s * exp2f(-0.41524101186092029f * (float)d);
        float sn, c;
        sincosf(theta, &sn, &c);
        rt[i] = make_float2(c, sn);
    }
}

// ---------------- GEMM mainloop: C = A(MxK) * B^T(NxK), K=1024 ----------------
// 128x128 tile, BK=64, unpadded 128x64 LDS tiles, global_load_lds width-16 staging.
// (R11 lesson: keep 8-lane/row 128B-segment staging — frag-order source halved
// segment size and LOST 19 µs despite zeroing bank conflicts.)
__device__ __forceinline__ void gemm_mainloop(
    const unsigned short* __restrict__ A,
    const unsigned short* __restrict__ Bw,
    unsigned short* At, unsigned short* Bt,
    f32x4 acc[4][4], int m0, int n0)
{
    const int tid  = threadIdx.x;
    const int lane = tid & 63;
    const int wave = tid >> 6;
    const int wr = wave >> 1, wc = wave & 1;
    const int lh = lane >> 4, ll = lane & 15;
    const int K = 1024;

    for (int k0 = 0; k0 < K; k0 += 64){
        #pragma unroll
        for (int c = 0; c < 4; ++c){
            int g   = c*256 + tid;          // 0..1023 16B chunks
            int row = g >> 3;               // 0..127
            int off = (g & 7) * 8;          // element offset in BK
            int base = (c*256 + wave*64) * 8;   // wave-uniform LDS element base
            ld16(A  + (size_t)(m0+row)*K + k0 + off, At + base);
            ld16(Bw + (size_t)(n0+row)*K + k0 + off, Bt + base);
        }
        __syncthreads();
        #pragma unroll
        for (int ks = 0; ks < 2; ++ks){
            bf16x8 af[4], bfr[4];
            #pragma unroll
            for (int i = 0; i < 4; ++i)
                af[i] = *(const bf16x8*)(At + (wr*64 + i*16 + ll)*64 + ks*32 + lh*8);
            #pragma unroll
            for (int j = 0; j < 4; ++j)
                bfr[j] = *(const bf16x8*)(Bt + (wc*64 + j*16 + ll)*64 + ks*32 + lh*8);
            #pragma unroll
            for (int i = 0; i < 4; ++i)
                #pragma unroll
                for (int j = 0; j < 4; ++j)
                    acc[i][j] = __builtin_amdgcn_mfma_f32_16x16x32_bf16(af[i], bfr[j], acc[i][j], 0, 0, 0);
        }
        __syncthreads();
    }
}

// ---------------- fragment-layout addressing for Q/K/VT tensors ----------------
// Per (bh, key-tile kt of 64): 8 fragments of 1KB. frag = ks*4 + j (K/Q: j = row
// group, ks = d/32) or ks*4 + t (V: t = d group, ks = key/32). Within a fragment,
// lane l = lh*16+ll holds 8 contiguous bf16 at offset l*8.
#define TILE_US 4096   // ushorts per (bh, kt) tile: 8 frags * 512

// XCD-aware swizzle for 512-block (x,y) grids: id%8 = XCD (round-robin dispatch;
// for gemm_qkv's z-slices, 512%8==0 keeps the pattern exact per slice). XCD c owns
// m-panels ys in [8c, 8c+8) across ALL n-strips -> each A-panel is fetched by one
// XCD's L2. Bijection: id = bx + 8*by -> xs = id/64, t = id%64, ys = (t%8)*8 + t/8.
__device__ __forceinline__ void swz_xy(int& xs, int& ys){
    int id = blockIdx.x + 8*blockIdx.y;
    xs = id >> 6;
    int t = id & 63;
    ys = (t & 7)*8 + (t >> 3);
}

// QKV projection with fused RoPE (Q,K) and fused transpose (V->VT). grid (8, 64, 3)
// launch_bounds (256,4) + XCD swizzle.
__global__ __launch_bounds__(256, 4) void gemm_qkv(
    const unsigned short* __restrict__ Xb,
    const unsigned short* __restrict__ Wq,
    const unsigned short* __restrict__ Wk,
    const unsigned short* __restrict__ Wv,
    const float2* __restrict__ Rt,
    unsigned short* __restrict__ Qt,
    unsigned short* __restrict__ Kt,
    unsigned short* __restrict__ VTt)
{
    __shared__ alignas(16) unsigned short At[128*64];
    __shared__ alignas(16) unsigned short Bt[128*64];
    const int z = blockIdx.z;
    const unsigned short* Bw = (z == 0) ? Wq : (z == 1 ? Wk : Wv);
    int xs, ys;
    swz_xy(xs, ys);
    const int m0 = ys * 128, n0 = xs * 128;
    f32x4 acc[4][4] = {};
    gemm_mainloop(Xb, Bw, At, Bt, acc, m0, n0);

    const int lane = threadIdx.x & 63;
    const int wave = threadIdx.x >> 6;
    const int wr = wave >> 1, wc = wave & 1;
    const int lh = lane >> 4, ll = lane & 15;
    const int h  = xs*2 + wc;                  // head index (n0+wc*64)/64
    const int b  = m0 >> 11;                    // batch (m0 128-aligned -> constant)
    const int bh = b*NH + h;

    if (z < 2){
        // RoPE: y_d = x_d*cos - x_{d+32}*sin ; y_{d+32} = x_{d+32}*cos + x_d*sin
        const float qs = (z == 0) ? 0.125f * 1.44269504f : 1.0f;  // fold 1/sqrt(64)*log2e into Q
        unsigned short* C = (z == 0) ? Qt : Kt;
        #pragma unroll
        for (int i = 0; i < 4; ++i)
            #pragma unroll
            for (int r = 0; r < 4; ++r){
                int m = m0 + wr*64 + i*16 + lh*4 + r;
                int s = m & (SS-1);
                int kt = s >> 6;
                const float2* rowcs = Rt + (s << 5);
                size_t fb = ((size_t)(bh*NT + kt)*8 + i)*512 + (size_t)(lh*4 + r)*8;
                #pragma unroll
                for (int jl = 0; jl < 2; ++jl){
                    int d_lo = jl*16 + ll;                     // 0..31
                    float2 cs = rowcs[d_lo];
                    float a_lo = acc[i][jl][r], a_hi = acc[i][jl+2][r];
                    float y_lo = (a_lo*cs.x - a_hi*cs.y) * qs;
                    float y_hi = (a_hi*cs.x + a_lo*cs.y) * qs;
                    size_t off = fb + (size_t)(jl*2 + (ll>>3))*128 + (ll&7);
                    C[off]        = f2b(y_lo);      // ks=0 frag
                    C[off + 2048] = f2b(y_hi);      // ks=1 frag
                }
            }
    } else {
        // V -> fragment layout. Element (key s, d): s-in-tile = i*16+lh*4+r.
        const int s0 = (m0 & (SS-1)) + wr*64;      // 64-aligned
        const int kt = s0 >> 6;
        #pragma unroll
        for (int i = 0; i < 4; ++i)
            #pragma unroll
            for (int j = 0; j < 4; ++j){
                unsigned short tmp[4];
                #pragma unroll
                for (int r = 0; r < 4; ++r)
                    tmp[r] = f2b(acc[i][j][r]);
                size_t off = ((size_t)(bh*NT + kt)*8 + (i>>1)*4 + j)*512
                           + (size_t)(((i&1)*2 + (lh>>1))*16 + ll)*8 + (lh&1)*4;
                *(uint2*)(VTt + off) = *(const uint2*)tmp;
            }
    }
}

// Output projection: fp32 out, row-major. grid (8, 64), XCD-swizzled.
__global__ __launch_bounds__(256, 4) void gemm_out(
    const unsigned short* __restrict__ Ab,
    const unsigned short* __restrict__ Wo,
    float* __restrict__ Cout)
{
    __shared__ alignas(16) unsigned short At[128*64];
    __shared__ alignas(16) unsigned short Bt[128*64];
    int xs, ys;
    swz_xy(xs, ys);
    const int m0 = ys * 128, n0 = xs * 128;
    f32x4 acc[4][4] = {};
    gemm_mainloop(Ab, Wo, At, Bt, acc, m0, n0);

    const int lane = threadIdx.x & 63;
    const int wave = threadIdx.x >> 6;
    const int wr = wave >> 1, wc = wave & 1;
    const int lh = lane >> 4, ll = lane & 15;
    #pragma unroll
    for (int i = 0; i < 4; ++i)
        #pragma unroll
        for (int j = 0; j < 4; ++j)
            #pragma unroll
            for (int r = 0; r < 4; ++r){
                int m = m0 + wr*64 + i*16 + lh*4 + r;
                int n = n0 + wc*64 + j*16 + ll;
                Cout[(size_t)m*BDIM + n] = acc[i][j][r];
            }
}

// ------------- attention tile: swapped QK^T + in-register P (T12) --------------------
// sc[j] = mfma(K_frag, Q_frag): lane (lh,ll) holds score(qrow=wsl*16+ll, key=16j+4lh+r).
// PV A-frag built per 32-key block via cvt_pk + permlane32/16 swaps — no LDS round-trip.
__device__ __forceinline__ void attn_tile(
    const bf16x8 qf[2], bool diag, int wsl, int lane, int lh, int ll,
    const unsigned short* Ksh, const unsigned short* Vsh,
    float& li, f32x4 o[4])
{
    f32x4 sc[4] = {};
    #pragma unroll
    for (int ks = 0; ks < 2; ++ks)
        #pragma unroll
        for (int j = 0; j < 4; ++j){
            bf16x8 kfr = *(const bf16x8*)(Ksh + (ks*4 + j)*512 + lane*8);
            sc[j] = __builtin_amdgcn_mfma_f32_16x16x32_bf16(kfr, qf[ks], sc[j], 0, 0, 0);
        }
    if (diag){
        int qrow = wsl*16 + ll;
        #pragma unroll
        for (int j = 0; j < 4; ++j)
            #pragma unroll
            for (int r = 0; r < 4; ++r)
                if (j*16 + lh*4 + r > qrow) sc[j][r] = -1e30f;
    }
    #pragma unroll
    for (int j = 0; j < 4; ++j)
        #pragma unroll
        for (int r = 0; r < 4; ++r)
            sc[j][r] = exp2f(sc[j][r] - 28.0f);
    float s = 0.f;
    #pragma unroll
    for (int j = 0; j < 4; ++j)
        s += (sc[j][0] + sc[j][1]) + (sc[j][2] + sc[j][3]);
    li += s;
    #pragma unroll
    for (int ks = 0; ks < 2; ++ks){
        unsigned a = cvtpk(sc[2*ks][0],   sc[2*ks][1]);
        unsigned b = cvtpk(sc[2*ks+1][0], sc[2*ks+1][1]);
        unsigned c = cvtpk(sc[2*ks][2],   sc[2*ks][3]);
        unsigned d = cvtpk(sc[2*ks+1][2], sc[2*ks+1][3]);
        asm("v_permlane32_swap_b32 %0, %1" : "+v"(a), "+v"(b));
        asm("v_permlane16_swap_b32 %0, %1" : "+v"(a), "+v"(b));
        asm("v_permlane32_swap_b32 %0, %1" : "+v"(c), "+v"(d));
        asm("v_permlane16_swap_b32 %0, %1" : "+v"(c), "+v"(d));
        uint4 uu = make_uint4(a, c, b, d);        // U0,U1,U2,U3
        bf16x8 pf = __builtin_bit_cast(bf16x8, uu);
        #pragma unroll
        for (int t = 0; t < 4; ++t){
            bf16x8 vf = *(const bf16x8*)(Vsh + (ks*4 + t)*512 + lane*8);
            o[t] = __builtin_amdgcn_mfma_f32_16x16x32_bf16(pf, vf, o[t], 0, 0, 0);
        }
    }
}

// epilogue: stage C-layout acc through per-wave LDS, emit 16B vector stores.
__device__ __forceinline__ void store_o(
    unsigned short* S, const f32x4 o[4], const float li[4],
    int lane, int lh, int ll, int q0w, int b, int h,
    unsigned short* __restrict__ Obuf)
{
    #pragma unroll
    for (int r = 0; r < 4; ++r){
        float inv = 1.0f / li[r];
        #pragma unroll
        for (int t = 0; t < 4; ++t)
            S[(lh*4 + r)*72 + t*16 + ll] = f2b(o[t][r] * inv);
    }
    int row = lane >> 2, c4 = (lane & 3) * 8;
    size_t rb = ((size_t)(b*SS + q0w + row))*BDIM + h*HD;
    *(uint4*)(Obuf + rb + c4)      = *(uint4*)(S + row*72 + c4);
    *(uint4*)(Obuf + rb + 32 + c4) = *(uint4*)(S + row*72 + 32 + c4);
}

// ------------ flash attention: ONE 128-row Q-tile per block, grid (16,64) ------------
// R14 post-mortem: occupancy pinned at 33% across 3 structural fixes -> the leak is
// the GRID (512 paired blocks = 2/CU, no backfill, unequal loop lengths). This
// version: 1024 single-tile blocks, 8 waves = 8 strips of the same tile (keeps R13's
// wave-uniform activity). LPT: sid = bx+16*by, T = 15-(sid>>6) -> the 64 heaviest
// blocks (T=15, 32 iters) dispatch FIRST, light ones backfill (anti-R5). bh = sid&63
// -> all 16 blocks of a bh share one XCD (sid%8 == bh%8): K/V L2 locality.
// LDS 32KB (store_o staging overlaid on K/V buffers after the loop; per-wave-private,
// in-order DS) -> 4 blocks/CU = 32 waves/CU hw max. launch_bounds(512,8) caps VGPR
// at 64 (single-tile state ~55; R14 dual-state was 60). Staging +36% but K/V is
// L2/L3-resident (32MB unique). Per-strip kt order identical -> bit-identical output.
__global__ __launch_bounds__(512, 8) void attn_kernel(
    const unsigned short* __restrict__ Qt,
    const unsigned short* __restrict__ Kt,
    const unsigned short* __restrict__ VTt,
    unsigned short* __restrict__ Obuf)
{
    __shared__ alignas(16) unsigned short SH[4*TILE_US];   // 32KB: K0,K1,V0,V1

    const int tid  = threadIdx.x;
    const int lane = tid & 63;
    const int wave = tid >> 6;       // 0..7: strip of the 128-row tile
    const int wsl  = wave & 3;       // strip within the 64-row kt-tile
    const int wsh  = wave >> 2;      // which 64-row half of the 128-row tile
    const int lh = lane >> 4, ll = lane & 15;

    const int sid = blockIdx.x + 16*blockIdx.y;
    const int T   = 15 - (sid >> 6);     // LPT: heavy tiles dispatch first
    const int bh  = sid & 63;

    const int d     = 2*T + wsh;     // this wave's diag kt (last active)
    const int ktMax = 2*T + 1;       // block loop bound (>= 1)

    const unsigned short* Qhf = Qt  + (size_t)bh * NT * TILE_US;
    const unsigned short* Khf = Kt  + (size_t)bh * NT * TILE_US;
    const unsigned short* Vhf = VTt + (size_t)bh * NT * TILE_US;

    bf16x8 qf[2];
    #pragma unroll
    for (int ks = 0; ks < 2; ++ks)
        qf[ks] = *(const bf16x8*)(Qhf + (size_t)(d*8 + ks*4 + wsl)*512 + lane*8);

    f32x4 o[4] = {};
    float li = 0.f;

    const int tb = tid * 8;              // ushort offset of this thread's 16B chunk

    // prologue: stage tile 0 -> buf0; issue tile 1 loads (consumed end of iter 0).
    {
        uint4 k0 = *(const uint4*)(Khf + tb);
        uint4 v0 = *(const uint4*)(Vhf + tb);
        *(uint4*)(SH + 0*TILE_US + tb) = k0;       // K buf0
        *(uint4*)(SH + 2*TILE_US + tb) = v0;       // V buf0
    }
    uint4 krC = *(const uint4*)(Khf + (size_t)TILE_US + tb);   // tile 1 (ktMax >= 1)
    uint4 vrC = *(const uint4*)(Vhf + (size_t)TILE_US + tb);
    __syncthreads();

    int cur = 0;
    for (int kt = 0; kt <= ktMax; ++kt){
        uint4 krN, vrN;
        if (kt + 2 <= ktMax){            // 2-deep: issue tile kt+2 (consumed end kt+1)
            size_t nb = (size_t)(kt + 2) * TILE_US + tb;
            krN = *(const uint4*)(Khf + nb);
            vrN = *(const uint4*)(Vhf + nb);
        }
        if (kt <= d)
            attn_tile(qf, kt == d, wsl, lane, lh, ll,
                      SH + cur*TILE_US, SH + (2+cur)*TILE_US, li, o);
        if (kt < ktMax){                 // write tile kt+1 -> other buffer
            *(uint4*)(SH + (cur^1)*TILE_US + tb) = krC;
            *(uint4*)(SH + (2+(cur^1))*TILE_US + tb) = vrC;
        }
        __syncthreads();                 // publish buf[cur^1]; all reads of buf[cur] done
        krC = krN; vrC = vrN;
        cur ^= 1;
    }

    // li: per-lane partial for qrow=ll over this lane's 16 keys/tile.
    li += __shfl_xor(li, 16); li += __shfl_xor(li, 32);
    float liv[4];
    #pragma unroll
    for (int r = 0; r < 4; ++r)
        liv[r] = __shfl(li, lh*4 + r);   // lane (lh*4+r) has ll = lh*4+r

    // store_o staging overlaid on SH (loop done; per-wave-private 1152-ushort region,
    // same-wave DS in-order -> no barrier needed).
    int b = bh >> 4, h = bh & 15;
    store_o(SH + wave*1152, o, liv, lane, lh, ll, T*128 + wave*16, b, h, Obuf);
}

extern "C" void kernel_launch(void* const* d_in, const int* in_sizes, int n_in,
                              void* d_out, int out_size, void* d_ws, size_t ws_size,
                              hipStream_t stream) {
    const float* x  = (const float*)d_in[0];
    const float* Wq = (const float*)d_in[1];
    const float* Wk = (const float*)d_in[2];
    const float* Wv = (const float*)d_in[3];
    const float* Wo = (const float*)d_in[4];
    // d_in[5] = mask: pure tril causal, handled analytically.

    char* w = (char*)d_ws;
    unsigned short* xb  = (unsigned short*)(w);                    // 16 MB
    unsigned short* wqb = (unsigned short*)(w + (16u  << 20));     // 2 MB each
    unsigned short* wkb = (unsigned short*)(w + (18u  << 20));
    unsigned short* wvb = (unsigned short*)(w + (20u  << 20));
    unsigned short* wob = (unsigned short*)(w + (22u  << 20));
    unsigned short* Qt  = (unsigned short*)(w + (24u  << 20));     // 16 MB each
    unsigned short* Kt  = (unsigned short*)(w + (40u  << 20));
    unsigned short* VTt = (unsigned short*)(w + (56u  << 20));
    unsigned short* Ob  = (unsigned short*)(w + (72u  << 20));     // 16 MB
    float2*         Rt  = (float2*)(w + (88u << 20));              // 512 KB rope table

    setup_all<<<12544, 256, 0, stream>>>(x, Wq, Wk, Wv, Wo, xb, wqb, wkb, wvb, wob, Rt);

    gemm_qkv<<<dim3(8, 64, 3), 256, 0, stream>>>(xb, wqb, wkb, wvb, Rt, Qt, Kt, VTt);
    attn_kernel<<<dim3(16, 64), 512, 0, stream>>>(Qt, Kt, VTt, Ob);
    gemm_out<<<dim3(8, 64), 256, 0, stream>>>(Ob, wob, (float*)d_out);
}

// Round 16
// 257.203 us; speedup vs baseline: 1.4496x; 1.4496x over previous
//
#include <hip/hip_runtime.h>
#include <hip/hip_bf16.h>

#define BDIM 1024
#define NH 16
#define HD 64
#define BB 4
#define SS 2048
#define MTOT (BB*SS)   // 8192
#define NT (SS/64)     // 32 key tiles

typedef __bf16 bf16x8 __attribute__((ext_vector_type(8)));
typedef float f32x4 __attribute__((ext_vector_type(4)));

// native HW bf16 convert (v_cvt_pk_bf16_f32; compiler packs pairs) — RNE.
__device__ __forceinline__ unsigned short f2b(float f){
    __bf16 h = (__bf16)f;
    return __builtin_bit_cast(unsigned short, h);
}

// v_cvt_pk_bf16_f32: lo -> bits[15:0], hi -> bits[31:16], RNE (same as f2b).
__device__ __forceinline__ unsigned cvtpk(float lo, float hi){
    unsigned u;
    asm("v_cvt_pk_bf16_f32 %0, %1, %2" : "=v"(u) : "v"(lo), "v"(hi));
    return u;
}

// async global->LDS, 16B per lane. LDS dest is wave-uniform base + lane*16.
__device__ __forceinline__ void ld16(const unsigned short* g, unsigned short* l){
    __builtin_amdgcn_global_load_lds(
        (const __attribute__((address_space(1))) unsigned int*)(const void*)g,
        (__attribute__((address_space(3))) unsigned int*)(void*)l, 16, 0, 0);
}

// ---------------- merged setup: x->bf16, weights->bf16, rope table ----------------
// grid 12544 x 256: [0,8192) x-convert, [8192,12288) weights, [12288,12544) rope.
__global__ void setup_all(const float* __restrict__ x,
                          const float* __restrict__ Wq, const float* __restrict__ Wk,
                          const float* __restrict__ Wv, const float* __restrict__ Wo,
                          unsigned short* __restrict__ xb,
                          unsigned short* __restrict__ oq, unsigned short* __restrict__ ok,
                          unsigned short* __restrict__ ov, unsigned short* __restrict__ oo,
                          float2* __restrict__ rt){
    const int bid = blockIdx.x;
    const int tid = threadIdx.x;
    if (bid < 8192){
        int i = bid * 256 + tid;                       // 2,097,152 float4 chunks
        float4 v = ((const float4*)x)[i];
        ushort4 o;
        o.x = f2b(v.x); o.y = f2b(v.y); o.z = f2b(v.z); o.w = f2b(v.w);
        ((ushort4*)xb)[i] = o;
    } else if (bid < 12288){
        int idx = bid - 8192;
        int which = idx >> 10;                          // 1024 blocks per weight
        const float* in = (which == 0) ? Wq : (which == 1) ? Wk : (which == 2) ? Wv : Wo;
        unsigned short* out = (which == 0) ? oq : (which == 1) ? ok : (which == 2) ? ov : oo;
        int i = (idx & 1023) * 256 + tid;               // 262,144 float4 chunks
        float4 v = ((const float4*)in)[i];
        ushort4 o;
        o.x = f2b(v.x); o.y = f2b(v.y); o.z = f2b(v.z); o.w = f2b(v.w);
        ((ushort4*)out)[i] = o;
    } else {
        int i = (bid - 12288) * 256 + tid;              // 65,536 rope entries
        int s = i >> 5, d = i & 31;
        float theta = (float)s * exp2f(-0.41524101186092029f * (float)d);
        float sn, c;
        sincosf(theta, &sn, &c);
        rt[i] = make_float2(c, sn);
    }
}

// ---------------- GEMM mainloop: C = A(MxK) * B^T(NxK), K=1024 ----------------
// 128x128 tile, BK=64, unpadded 128x64 LDS tiles, global_load_lds width-16 staging.
// (R11 lesson: keep 8-lane/row 128B-segment staging — frag-order source halved
// segment size and LOST 19 µs despite zeroing bank conflicts.)
__device__ __forceinline__ void gemm_mainloop(
    const unsigned short* __restrict__ A,
    const unsigned short* __restrict__ Bw,
    unsigned short* At, unsigned short* Bt,
    f32x4 acc[4][4], int m0, int n0)
{
    const int tid  = threadIdx.x;
    const int lane = tid & 63;
    const int wave = tid >> 6;
    const int wr = wave >> 1, wc = wave & 1;
    const int lh = lane >> 4, ll = lane & 15;
    const int K = 1024;

    for (int k0 = 0; k0 < K; k0 += 64){
        #pragma unroll
        for (int c = 0; c < 4; ++c){
            int g   = c*256 + tid;          // 0..1023 16B chunks
            int row = g >> 3;               // 0..127
            int off = (g & 7) * 8;          // element offset in BK
            int base = (c*256 + wave*64) * 8;   // wave-uniform LDS element base
            ld16(A  + (size_t)(m0+row)*K + k0 + off, At + base);
            ld16(Bw + (size_t)(n0+row)*K + k0 + off, Bt + base);
        }
        __syncthreads();
        #pragma unroll
        for (int ks = 0; ks < 2; ++ks){
            bf16x8 af[4], bfr[4];
            #pragma unroll
            for (int i = 0; i < 4; ++i)
                af[i] = *(const bf16x8*)(At + (wr*64 + i*16 + ll)*64 + ks*32 + lh*8);
            #pragma unroll
            for (int j = 0; j < 4; ++j)
                bfr[j] = *(const bf16x8*)(Bt + (wc*64 + j*16 + ll)*64 + ks*32 + lh*8);
            #pragma unroll
            for (int i = 0; i < 4; ++i)
                #pragma unroll
                for (int j = 0; j < 4; ++j)
                    acc[i][j] = __builtin_amdgcn_mfma_f32_16x16x32_bf16(af[i], bfr[j], acc[i][j], 0, 0, 0);
        }
        __syncthreads();
    }
}

// ---------------- fragment-layout addressing for Q/K/VT tensors ----------------
// Per (bh, key-tile kt of 64): 8 fragments of 1KB. frag = ks*4 + j (K/Q: j = row
// group, ks = d/32) or ks*4 + t (V: t = d group, ks = key/32). Within a fragment,
// lane l = lh*16+ll holds 8 contiguous bf16 at offset l*8.
#define TILE_US 4096   // ushorts per (bh, kt) tile: 8 frags * 512

// XCD-aware swizzle for 512-block (x,y) grids: id%8 = XCD (round-robin dispatch;
// for gemm_qkv's z-slices, 512%8==0 keeps the pattern exact per slice). XCD c owns
// m-panels ys in [8c, 8c+8) across ALL n-strips -> each A-panel is fetched by one
// XCD's L2. Bijection: id = bx + 8*by -> xs = id/64, t = id%64, ys = (t%8)*8 + t/8.
__device__ __forceinline__ void swz_xy(int& xs, int& ys){
    int id = blockIdx.x + 8*blockIdx.y;
    xs = id >> 6;
    int t = id & 63;
    ys = (t & 7)*8 + (t >> 3);
}

// QKV projection with fused RoPE (Q,K) and fused transpose (V->VT). grid (8, 64, 3)
// launch_bounds (256,4) + XCD swizzle.
__global__ __launch_bounds__(256, 4) void gemm_qkv(
    const unsigned short* __restrict__ Xb,
    const unsigned short* __restrict__ Wq,
    const unsigned short* __restrict__ Wk,
    const unsigned short* __restrict__ Wv,
    const float2* __restrict__ Rt,
    unsigned short* __restrict__ Qt,
    unsigned short* __restrict__ Kt,
    unsigned short* __restrict__ VTt)
{
    __shared__ alignas(16) unsigned short At[128*64];
    __shared__ alignas(16) unsigned short Bt[128*64];
    const int z = blockIdx.z;
    const unsigned short* Bw = (z == 0) ? Wq : (z == 1 ? Wk : Wv);
    int xs, ys;
    swz_xy(xs, ys);
    const int m0 = ys * 128, n0 = xs * 128;
    f32x4 acc[4][4] = {};
    gemm_mainloop(Xb, Bw, At, Bt, acc, m0, n0);

    const int lane = threadIdx.x & 63;
    const int wave = threadIdx.x >> 6;
    const int wr = wave >> 1, wc = wave & 1;
    const int lh = lane >> 4, ll = lane & 15;
    const int h  = xs*2 + wc;                  // head index (n0+wc*64)/64
    const int b  = m0 >> 11;                    // batch (m0 128-aligned -> constant)
    const int bh = b*NH + h;

    if (z < 2){
        // RoPE: y_d = x_d*cos - x_{d+32}*sin ; y_{d+32} = x_{d+32}*cos + x_d*sin
        const float qs = (z == 0) ? 0.125f * 1.44269504f : 1.0f;  // fold 1/sqrt(64)*log2e into Q
        unsigned short* C = (z == 0) ? Qt : Kt;
        #pragma unroll
        for (int i = 0; i < 4; ++i)
            #pragma unroll
            for (int r = 0; r < 4; ++r){
                int m = m0 + wr*64 + i*16 + lh*4 + r;
                int s = m & (SS-1);
                int kt = s >> 6;
                const float2* rowcs = Rt + (s << 5);
                size_t fb = ((size_t)(bh*NT + kt)*8 + i)*512 + (size_t)(lh*4 + r)*8;
                #pragma unroll
                for (int jl = 0; jl < 2; ++jl){
                    int d_lo = jl*16 + ll;                     // 0..31
                    float2 cs = rowcs[d_lo];
                    float a_lo = acc[i][jl][r], a_hi = acc[i][jl+2][r];
                    float y_lo = (a_lo*cs.x - a_hi*cs.y) * qs;
                    float y_hi = (a_hi*cs.x + a_lo*cs.y) * qs;
                    size_t off = fb + (size_t)(jl*2 + (ll>>3))*128 + (ll&7);
                    C[off]        = f2b(y_lo);      // ks=0 frag
                    C[off + 2048] = f2b(y_hi);      // ks=1 frag
                }
            }
    } else {
        // V -> fragment layout. Element (key s, d): s-in-tile = i*16+lh*4+r.
        const int s0 = (m0 & (SS-1)) + wr*64;      // 64-aligned
        const int kt = s0 >> 6;
        #pragma unroll
        for (int i = 0; i < 4; ++i)
            #pragma unroll
            for (int j = 0; j < 4; ++j){
                unsigned short tmp[4];
                #pragma unroll
                for (int r = 0; r < 4; ++r)
                    tmp[r] = f2b(acc[i][j][r]);
                size_t off = ((size_t)(bh*NT + kt)*8 + (i>>1)*4 + j)*512
                           + (size_t)(((i&1)*2 + (lh>>1))*16 + ll)*8 + (lh&1)*4;
                *(uint2*)(VTt + off) = *(const uint2*)tmp;
            }
    }
}

// Output projection: fp32 out, row-major. grid (8, 64), XCD-swizzled.
__global__ __launch_bounds__(256, 4) void gemm_out(
    const unsigned short* __restrict__ Ab,
    const unsigned short* __restrict__ Wo,
    float* __restrict__ Cout)
{
    __shared__ alignas(16) unsigned short At[128*64];
    __shared__ alignas(16) unsigned short Bt[128*64];
    int xs, ys;
    swz_xy(xs, ys);
    const int m0 = ys * 128, n0 = xs * 128;
    f32x4 acc[4][4] = {};
    gemm_mainloop(Ab, Wo, At, Bt, acc, m0, n0);

    const int lane = threadIdx.x & 63;
    const int wave = threadIdx.x >> 6;
    const int wr = wave >> 1, wc = wave & 1;
    const int lh = lane >> 4, ll = lane & 15;
    #pragma unroll
    for (int i = 0; i < 4; ++i)
        #pragma unroll
        for (int j = 0; j < 4; ++j)
            #pragma unroll
            for (int r = 0; r < 4; ++r){
                int m = m0 + wr*64 + i*16 + lh*4 + r;
                int n = n0 + wc*64 + j*16 + ll;
                Cout[(size_t)m*BDIM + n] = acc[i][j][r];
            }
}

// ------------- attention tile: swapped QK^T + in-register P (T12) --------------------
// sc[j] = mfma(K_frag, Q_frag): lane (lh,ll) holds score(qrow=wsl*16+ll, key=16j+4lh+r).
// PV A-frag built per 32-key block via cvt_pk + permlane32/16 swaps — no LDS round-trip.
__device__ __forceinline__ void attn_tile(
    const bf16x8 qf[2], bool diag, int wsl, int lane, int lh, int ll,
    const unsigned short* Ksh, const unsigned short* Vsh,
    float& li, f32x4 o[4])
{
    f32x4 sc[4] = {};
    #pragma unroll
    for (int ks = 0; ks < 2; ++ks)
        #pragma unroll
        for (int j = 0; j < 4; ++j){
            bf16x8 kfr = *(const bf16x8*)(Ksh + (ks*4 + j)*512 + lane*8);
            sc[j] = __builtin_amdgcn_mfma_f32_16x16x32_bf16(kfr, qf[ks], sc[j], 0, 0, 0);
        }
    if (diag){
        int qrow = wsl*16 + ll;
        #pragma unroll
        for (int j = 0; j < 4; ++j)
            #pragma unroll
            for (int r = 0; r < 4; ++r)
                if (j*16 + lh*4 + r > qrow) sc[j][r] = -1e30f;
    }
    #pragma unroll
    for (int j = 0; j < 4; ++j)
        #pragma unroll
        for (int r = 0; r < 4; ++r)
            sc[j][r] = exp2f(sc[j][r] - 28.0f);
    float s = 0.f;
    #pragma unroll
    for (int j = 0; j < 4; ++j)
        s += (sc[j][0] + sc[j][1]) + (sc[j][2] + sc[j][3]);
    li += s;
    #pragma unroll
    for (int ks = 0; ks < 2; ++ks){
        unsigned a = cvtpk(sc[2*ks][0],   sc[2*ks][1]);
        unsigned b = cvtpk(sc[2*ks+1][0], sc[2*ks+1][1]);
        unsigned c = cvtpk(sc[2*ks][2],   sc[2*ks][3]);
        unsigned d = cvtpk(sc[2*ks+1][2], sc[2*ks+1][3]);
        asm("v_permlane32_swap_b32 %0, %1" : "+v"(a), "+v"(b));
        asm("v_permlane16_swap_b32 %0, %1" : "+v"(a), "+v"(b));
        asm("v_permlane32_swap_b32 %0, %1" : "+v"(c), "+v"(d));
        asm("v_permlane16_swap_b32 %0, %1" : "+v"(c), "+v"(d));
        uint4 uu = make_uint4(a, c, b, d);        // U0,U1,U2,U3
        bf16x8 pf = __builtin_bit_cast(bf16x8, uu);
        #pragma unroll
        for (int t = 0; t < 4; ++t){
            bf16x8 vf = *(const bf16x8*)(Vsh + (ks*4 + t)*512 + lane*8);
            o[t] = __builtin_amdgcn_mfma_f32_16x16x32_bf16(pf, vf, o[t], 0, 0, 0);
        }
    }
}

// epilogue: stage C-layout acc through per-wave LDS, emit 16B vector stores.
__device__ __forceinline__ void store_o(
    unsigned short* S, const f32x4 o[4], const float li[4],
    int lane, int lh, int ll, int q0w, int b, int h,
    unsigned short* __restrict__ Obuf)
{
    #pragma unroll
    for (int r = 0; r < 4; ++r){
        float inv = 1.0f / li[r];
        #pragma unroll
        for (int t = 0; t < 4; ++t)
            S[(lh*4 + r)*72 + t*16 + ll] = f2b(o[t][r] * inv);
    }
    int row = lane >> 2, c4 = (lane & 3) * 8;
    size_t rb = ((size_t)(b*SS + q0w + row))*BDIM + h*HD;
    *(uint4*)(Obuf + rb + c4)      = *(uint4*)(S + row*72 + c4);
    *(uint4*)(Obuf + rb + 32 + c4) = *(uint4*)(S + row*72 + 32 + c4);
}

// ------------ flash attention: ONE 128-row Q-tile per block, grid (16,64) ------------
// R15 structure (single-tile blocks, LPT heavy-first, 32KB LDS, store_o overlay) with
// the spill fixed: launch_bounds (512,4) not (512,8). R15's (512,8) capped the
// allocator at 32 VGPRs -> 500MB scratch WRITE, MfmaUtil 7.7%. launch_bounds is a
// MINIMUM-occupancy guarantee: with ~50-60 VGPRs actually allocated and 32KB LDS the
// HW can still co-schedule 4 blocks/CU (LDS limit 5, wave-slot limit 4); LPT backfill
// fixes the R14 tail (occ was pinned 33% at 2 fixed blocks/CU).
// sid = bx+16*by, T = 15-(sid>>6) (heavy first), bh = sid&63 (sid%8==bh%8 -> one XCD
// per bh: K/V L2 locality). Per-strip kt order identical -> bit-identical output.
__global__ __launch_bounds__(512, 4) void attn_kernel(
    const unsigned short* __restrict__ Qt,
    const unsigned short* __restrict__ Kt,
    const unsigned short* __restrict__ VTt,
    unsigned short* __restrict__ Obuf)
{
    __shared__ alignas(16) unsigned short SH[4*TILE_US];   // 32KB: K0,K1,V0,V1

    const int tid  = threadIdx.x;
    const int lane = tid & 63;
    const int wave = tid >> 6;       // 0..7: strip of the 128-row tile
    const int wsl  = wave & 3;       // strip within the 64-row kt-tile
    const int wsh  = wave >> 2;      // which 64-row half of the 128-row tile
    const int lh = lane >> 4, ll = lane & 15;

    const int sid = blockIdx.x + 16*blockIdx.y;
    const int T   = 15 - (sid >> 6);     // LPT: heavy tiles dispatch first
    const int bh  = sid & 63;

    const int d     = 2*T + wsh;     // this wave's diag kt (last active)
    const int ktMax = 2*T + 1;       // block loop bound (>= 1)

    const unsigned short* Qhf = Qt  + (size_t)bh * NT * TILE_US;
    const unsigned short* Khf = Kt  + (size_t)bh * NT * TILE_US;
    const unsigned short* Vhf = VTt + (size_t)bh * NT * TILE_US;

    bf16x8 qf[2];
    #pragma unroll
    for (int ks = 0; ks < 2; ++ks)
        qf[ks] = *(const bf16x8*)(Qhf + (size_t)(d*8 + ks*4 + wsl)*512 + lane*8);

    f32x4 o[4] = {};
    float li = 0.f;

    const int tb = tid * 8;              // ushort offset of this thread's 16B chunk

    // prologue: stage tile 0 -> buf0; issue tile 1 loads (consumed end of iter 0).
    {
        uint4 k0 = *(const uint4*)(Khf + tb);
        uint4 v0 = *(const uint4*)(Vhf + tb);
        *(uint4*)(SH + 0*TILE_US + tb) = k0;       // K buf0
        *(uint4*)(SH + 2*TILE_US + tb) = v0;       // V buf0
    }
    uint4 krC = *(const uint4*)(Khf + (size_t)TILE_US + tb);   // tile 1 (ktMax >= 1)
    uint4 vrC = *(const uint4*)(Vhf + (size_t)TILE_US + tb);
    __syncthreads();

    int cur = 0;
    for (int kt = 0; kt <= ktMax; ++kt){
        uint4 krN, vrN;
        if (kt + 2 <= ktMax){            // 2-deep: issue tile kt+2 (consumed end kt+1)
            size_t nb = (size_t)(kt + 2) * TILE_US + tb;
            krN = *(const uint4*)(Khf + nb);
            vrN = *(const uint4*)(Vhf + nb);
        }
        if (kt <= d)
            attn_tile(qf, kt == d, wsl, lane, lh, ll,
                      SH + cur*TILE_US, SH + (2+cur)*TILE_US, li, o);
        if (kt < ktMax){                 // write tile kt+1 -> other buffer
            *(uint4*)(SH + (cur^1)*TILE_US + tb) = krC;
            *(uint4*)(SH + (2+(cur^1))*TILE_US + tb) = vrC;
        }
        __syncthreads();                 // publish buf[cur^1]; all reads of buf[cur] done
        krC = krN; vrC = vrN;
        cur ^= 1;
    }

    // li: per-lane partial for qrow=ll over this lane's 16 keys/tile.
    li += __shfl_xor(li, 16); li += __shfl_xor(li, 32);
    float liv[4];
    #pragma unroll
    for (int r = 0; r < 4; ++r)
        liv[r] = __shfl(li, lh*4 + r);   // lane (lh*4+r) has ll = lh*4+r

    // store_o staging overlaid on SH (loop done; per-wave-private 1152-ushort region,
    // same-wave DS in-order -> no barrier needed).
    int b = bh >> 4, h = bh & 15;
    store_o(SH + wave*1152, o, liv, lane, lh, ll, T*128 + wave*16, b, h, Obuf);
}

extern "C" void kernel_launch(void* const* d_in, const int* in_sizes, int n_in,
                              void* d_out, int out_size, void* d_ws, size_t ws_size,
                              hipStream_t stream) {
    const float* x  = (const float*)d_in[0];
    const float* Wq = (const float*)d_in[1];
    const float* Wk = (const float*)d_in[2];
    const float* Wv = (const float*)d_in[3];
    const float* Wo = (const float*)d_in[4];
    // d_in[5] = mask: pure tril causal, handled analytically.

    char* w = (char*)d_ws;
    unsigned short* xb  = (unsigned short*)(w);                    // 16 MB
    unsigned short* wqb = (unsigned short*)(w + (16u  << 20));     // 2 MB each
    unsigned short* wkb = (unsigned short*)(w + (18u  << 20));
    unsigned short* wvb = (unsigned short*)(w + (20u  << 20));
    unsigned short* wob = (unsigned short*)(w + (22u  << 20));
    unsigned short* Qt  = (unsigned short*)(w + (24u  << 20));     // 16 MB each
    unsigned short* Kt  = (unsigned short*)(w + (40u  << 20));
    unsigned short* VTt = (unsigned short*)(w + (56u  << 20));
    unsigned short* Ob  = (unsigned short*)(w + (72u  << 20));     // 16 MB
    float2*         Rt  = (float2*)(w + (88u << 20));              // 512 KB rope table

    setup_all<<<12544, 256, 0, stream>>>(x, Wq, Wk, Wv, Wo, xb, wqb, wkb, wvb, wob, Rt);

    gemm_qkv<<<dim3(8, 64, 3), 256, 0, stream>>>(xb, wqb, wkb, wvb, Rt, Qt, Kt, VTt);
    attn_kernel<<<dim3(16, 64), 512, 0, stream>>>(Qt, Kt, VTt, Ob);
    gemm_out<<<dim3(8, 64), 256, 0, stream>>>(Ob, wob, (float*)d_out);
}